// Round 1
// baseline (536.117 us; speedup 1.0000x reference)
//
#include <hip/hip_runtime.h>

// EmbeddingBagCollection: F tables [N,D] fp32, jagged sum-pool per bag.
// out[b, f*D + d] = sum_{i in [offs[f][b], offs[f][b+1])} tables[f][values[f][i]][d]
#define F_TABLES 8
#define B_BAGS   8192
#define N_ROWS   200000
#define D_DIM    64
#define T_IDX    163840

// One wave per (f,b). 4 index-groups of 16 lanes; each group loads a full
// 256B row as float4 (16B/lane x 16 lanes) -> 4 gathers in flight per iter.
__global__ __launch_bounds__(256, 4) void ebc_pool_kernel(
    const float* __restrict__ tables,
    const int*   __restrict__ values,
    const int*   __restrict__ offsets,
    float*       __restrict__ out)
{
    const int wid  = blockIdx.x * (blockDim.x >> 6) + (threadIdx.x >> 6);
    const int lane = threadIdx.x & 63;
    const int f = wid >> 13;        // wid / B_BAGS
    const int b = wid & (B_BAGS - 1);

    const float4* __restrict__ tab =
        (const float4*)(tables + (size_t)f * N_ROWS * D_DIM);
    const int* __restrict__ vals = values + f * T_IDX;

    const int obase = f * (B_BAGS + 1) + b;
    const int start = offsets[obase];
    const int end   = offsets[obase + 1];

    const int g = lane >> 4;   // index group 0..3
    const int c = lane & 15;   // float4 chunk within row

    float4 acc = make_float4(0.f, 0.f, 0.f, 0.f);
    for (int i = start + g; i < end; i += 4) {
        const int idx = vals[i];
        const float4 v = tab[(size_t)idx * (D_DIM / 4) + c];
        acc.x += v.x; acc.y += v.y; acc.z += v.z; acc.w += v.w;
    }

    // fold the 4 group-partials (lanes c, c+16, c+32, c+48 hold same dims)
    #pragma unroll
    for (int m = 16; m < 64; m <<= 1) {
        acc.x += __shfl_xor(acc.x, m, 64);
        acc.y += __shfl_xor(acc.y, m, 64);
        acc.z += __shfl_xor(acc.z, m, 64);
        acc.w += __shfl_xor(acc.w, m, 64);
    }

    if (lane < 16) {
        float4* o = (float4*)(out + (size_t)b * (F_TABLES * D_DIM) + f * D_DIM);
        o[c] = acc;
    }
}

extern "C" void kernel_launch(void* const* d_in, const int* in_sizes, int n_in,
                              void* d_out, int out_size, void* d_ws, size_t ws_size,
                              hipStream_t stream) {
    const float* tables  = (const float*)d_in[0];
    const int*   values  = (const int*)d_in[1];
    const int*   offsets = (const int*)d_in[2];
    float*       out     = (float*)d_out;

    // F*B = 65536 waves, 4 waves per 256-thread block -> 16384 blocks
    const int total_waves = F_TABLES * B_BAGS;
    const int blocks = total_waves / 4;
    hipLaunchKernelGGL(ebc_pool_kernel, dim3(blocks), dim3(256), 0, stream,
                       tables, values, offsets, out);
}